// Round 1
// baseline (425.680 us; speedup 1.0000x reference)
//
#include <hip/hip_runtime.h>
#include <cstdint>
#include <cstddef>

#define B_SZ    200
#define NNZ_ALL 1070638
#define OUT_ALL 89064
#define NL      13
#define NB1     349   // ceil(OUT_ALL/256)

__constant__ int c_nnz_off[NL + 1] = {0, 480000, 540000, 780000, 810000, 930000, 945000,
                                      1005000, 1012500, 1042500, 1046250, 1061258, 1063134, 1070638};
__constant__ int c_out_off[NL + 1] = {0, 30000, 45000, 60000, 67500, 75000, 78750,
                                      82500, 84375, 86250, 87188, 88126, 88595, 89064};

// ---------------- threefry2x32 (matches jax._src.prng) ----------------
__host__ __device__ inline void tf2x32(uint32_t k0, uint32_t k1, uint32_t& x0, uint32_t& x1) {
  uint32_t ks2 = k0 ^ k1 ^ 0x1BD11BDAu;
  x0 += k0; x1 += k1;
#define TF_ROT(v, d) (((v) << (d)) | ((v) >> (32 - (d))))
#define TF_R4(a, b, c, dd)                                   \
  { x0 += x1; x1 = TF_ROT(x1, a);  x1 ^= x0;                 \
    x0 += x1; x1 = TF_ROT(x1, b);  x1 ^= x0;                 \
    x0 += x1; x1 = TF_ROT(x1, c);  x1 ^= x0;                 \
    x0 += x1; x1 = TF_ROT(x1, dd); x1 ^= x0; }
  TF_R4(13, 15, 26, 6);  x0 += k1;  x1 += ks2 + 1u;
  TF_R4(17, 29, 16, 24); x0 += ks2; x1 += k0  + 2u;
  TF_R4(13, 15, 26, 6);  x0 += k0;  x1 += k1  + 3u;
  TF_R4(17, 29, 16, 24); x0 += k1;  x1 += ks2 + 4u;
  TF_R4(13, 15, 26, 6);  x0 += ks2; x1 += k0  + 5u;
#undef TF_R4
#undef TF_ROT
}

// partitionable threefry random bits for 32-bit: bits_i = o0 ^ o1, counter i (hi=0)
__device__ inline float jax_uniform01(uint32_t k0, uint32_t k1, uint32_t i) {
  uint32_t x0 = 0u, x1 = i;
  tf2x32(k0, k1, x0, x1);
  uint32_t bits = x0 ^ x1;
  return __uint_as_float((bits >> 9) | 0x3f800000u) - 1.0f;
}

// ---------------- transpose x (200 x 30000 row-major) -> xt (col-major, col stride 200)
__global__ void transpose_kernel(const float* __restrict__ x, float* __restrict__ xt) {
  __shared__ float tile[32][33];
  int s0 = blockIdx.x * 32;
  int b0 = blockIdx.y * 32;
#pragma unroll
  for (int j = 0; j < 4; ++j) {
    int b = b0 + threadIdx.y + j * 8;
    int s = s0 + threadIdx.x;
    if (b < B_SZ && s < 30000) tile[threadIdx.y + j * 8][threadIdx.x] = x[b * 30000 + s];
  }
  __syncthreads();
#pragma unroll
  for (int j = 0; j < 4; ++j) {
    int s = s0 + threadIdx.y + j * 8;
    int b = b0 + threadIdx.x;
    if (b < B_SZ && s < 30000) xt[s * B_SZ + b] = tile[threadIdx.x][threadIdx.y + j * 8];
  }
}

// ---------------- CSR build: histogram -> scan -> scatter ----------------
__device__ inline int edge_layer(int e) {
  int li = 0;
#pragma unroll
  for (int j = 1; j < NL; ++j) li += (e >= c_nnz_off[j]) ? 1 : 0;
  return li;
}

__global__ void hist_kernel(const int* __restrict__ dsts, int* __restrict__ counts) {
  int e = blockIdx.x * 256 + threadIdx.x;
  if (e >= NNZ_ALL) return;
  int li = edge_layer(e);
  atomicAdd(&counts[c_out_off[li] + dsts[e]], 1);
}

__global__ void scan1_kernel(const int* __restrict__ counts, int* __restrict__ ptr,
                             int* __restrict__ bsums) {
  __shared__ int sh[256];
  int t = threadIdx.x;
  int i = blockIdx.x * 256 + t;
  int v = (i < OUT_ALL) ? counts[i] : 0;
  sh[t] = v;
  __syncthreads();
  for (int o = 1; o < 256; o <<= 1) {
    int add = (t >= o) ? sh[t - o] : 0;
    __syncthreads();
    sh[t] += add;
    __syncthreads();
  }
  if (i < OUT_ALL) ptr[i] = sh[t] - v;          // exclusive within block
  if (t == 255) bsums[blockIdx.x] = sh[255];
}

__global__ void scan2_kernel(int* __restrict__ bsums) {
  __shared__ int sh[512];
  int t = threadIdx.x;
  int v = (t < NB1) ? bsums[t] : 0;
  sh[t] = v;
  __syncthreads();
  for (int o = 1; o < 512; o <<= 1) {
    int add = (t >= o) ? sh[t - o] : 0;
    __syncthreads();
    sh[t] += add;
    __syncthreads();
  }
  if (t < NB1) bsums[t] = sh[t] - v;            // exclusive block offsets
}

__global__ void scan3_kernel(int* __restrict__ ptr, const int* __restrict__ bsums,
                             int* __restrict__ cursor) {
  int i = blockIdx.x * 256 + threadIdx.x;
  if (i < OUT_ALL) {
    int p = ptr[i] + bsums[blockIdx.x];
    ptr[i] = p;
    cursor[i] = p;
  }
  if (i == 0) ptr[OUT_ALL] = NNZ_ALL;
}

__global__ void scatter_kernel(const int* __restrict__ srcs, const int* __restrict__ dsts,
                               const float* __restrict__ wmu, int* __restrict__ cursor,
                               int* __restrict__ ssrc, float* __restrict__ swv) {
  int e = blockIdx.x * 256 + threadIdx.x;
  if (e >= NNZ_ALL) return;
  int li = edge_layer(e);
  int slot = atomicAdd(&cursor[c_out_off[li] + dsts[e]], 1);
  ssrc[slot] = srcs[e];
  swv[slot]  = wmu[e];
}

// ---------------- KL ----------------
__global__ void kl_partial_kernel(const float* __restrict__ mu, const float* __restrict__ ls,
                                  float* __restrict__ part) {
  float s = 0.f;
  for (int i = blockIdx.x * 256 + threadIdx.x; i < NNZ_ALL; i += 512 * 256) {
    float m = mu[i], l = ls[i];
    s += expf(2.f * l) + m * m - 1.f - 2.f * l;
  }
#pragma unroll
  for (int o = 32; o > 0; o >>= 1) s += __shfl_down(s, o, 64);
  __shared__ float sh[4];
  if ((threadIdx.x & 63) == 0) sh[threadIdx.x >> 6] = s;
  __syncthreads();
  if (threadIdx.x == 0) part[blockIdx.x] = sh[0] + sh[1] + sh[2] + sh[3];
}

__global__ void kl_final_kernel(const float* __restrict__ part, float* __restrict__ out) {
  int t = threadIdx.x;   // 512 threads, part has 512 entries
  float s = part[t];
#pragma unroll
  for (int o = 32; o > 0; o >>= 1) s += __shfl_down(s, o, 64);
  __shared__ float sh[8];
  if ((t & 63) == 0) sh[t >> 6] = s;
  __syncthreads();
  if (t == 0) {
    float tot = 0.f;
#pragma unroll
    for (int i = 0; i < 8; ++i) tot += sh[i];
    out[0] = 0.5f * tot;
  }
}

// ---------------- pool layer (sparse gather + bias only) ----------------
// one block per output column; thread t<100 handles batch rows 2t, 2t+1 (float2)
__global__ __launch_bounds__(128) void pool_kernel(
    const float* __restrict__ hin, float* __restrict__ hout,
    const int* __restrict__ ptr, const int* __restrict__ ssrc, const float* __restrict__ swv,
    const float* __restrict__ bias, int col_base) {
  const int d = blockIdx.x;
  const int t = threadIdx.x;
  if (t >= 100) return;
  const int g = col_base + d;
  int e0 = ptr[g], e1 = ptr[g + 1];
  const float2* __restrict__ hin2 = (const float2*)hin;
  float bb = bias[g];
  float a0 = bb, a1 = bb;
  int e = e0;
  for (; e + 2 <= e1; e += 2) {
    int   sA = ssrc[e],  sB = ssrc[e + 1];
    float wA = swv[e],   wB = swv[e + 1];
    float2 hA = hin2[sA * 100 + t];
    float2 hB = hin2[sB * 100 + t];
    a0 = fmaf(hA.x, wA, a0); a1 = fmaf(hA.y, wA, a1);
    a0 = fmaf(hB.x, wB, a0); a1 = fmaf(hB.y, wB, a1);
  }
  if (e < e1) {
    int sA = ssrc[e]; float wA = swv[e];
    float2 hA = hin2[sA * 100 + t];
    a0 = fmaf(hA.x, wA, a0); a1 = fmaf(hA.y, wA, a1);
  }
  ((float2*)hout)[d * 100 + t] = make_float2(a0, a1);
}

// ---------------- lin layer fused with BN + ReLU + dropout ----------------
__global__ __launch_bounds__(128) void lin_bn_drop_kernel(
    const float* __restrict__ hin, float* __restrict__ hout,
    const int* __restrict__ ptr, const int* __restrict__ ssrc, const float* __restrict__ swv,
    const float* __restrict__ bias, const float* __restrict__ gamma, const float* __restrict__ beta,
    int col_base, int bn_base, int S, uint32_t k0, uint32_t k1) {
  const int d = blockIdx.x;
  const int t = threadIdx.x;
  const int g = col_base + d;
  const int e0 = ptr[g], e1 = ptr[g + 1];
  const float2* __restrict__ hin2 = (const float2*)hin;
  float a0 = 0.f, a1 = 0.f;
  if (t < 100) {
    int e = e0;
    for (; e + 2 <= e1; e += 2) {
      int   sA = ssrc[e],  sB = ssrc[e + 1];
      float wA = swv[e],   wB = swv[e + 1];
      float2 hA = hin2[sA * 100 + t];
      float2 hB = hin2[sB * 100 + t];
      a0 = fmaf(hA.x, wA, a0); a1 = fmaf(hA.y, wA, a1);
      a0 = fmaf(hB.x, wB, a0); a1 = fmaf(hB.y, wB, a1);
    }
    if (e < e1) {
      int sA = ssrc[e]; float wA = swv[e];
      float2 hA = hin2[sA * 100 + t];
      a0 = fmaf(hA.x, wA, a0); a1 = fmaf(hA.y, wA, a1);
    }
    float bb = bias[g];
    a0 += bb; a1 += bb;
  }
  // block reduce sum & sumsq over 200 values
  float s = a0 + a1;
  float q = a0 * a0 + a1 * a1;
#pragma unroll
  for (int o = 32; o > 0; o >>= 1) { s += __shfl_down(s, o, 64); q += __shfl_down(q, o, 64); }
  __shared__ float shs[2], shq[2];
  if ((t & 63) == 0) { shs[t >> 6] = s; shq[t >> 6] = q; }
  __syncthreads();
  float sum = shs[0] + shs[1];
  float ssq = shq[0] + shq[1];
  float m = sum * (1.0f / 200.0f);
  float v = ssq * (1.0f / 200.0f) - m * m;
  if (v < 0.f) v = 0.f;
  float rstd = 1.0f / sqrtf(v + 1e-5f);
  if (t < 100) {
    float ga = gamma[bn_base + d], be = beta[bn_base + d];
    float y0 = fmaf((a0 - m) * rstd, ga, be);
    float y1 = fmaf((a1 - m) * rstd, ga, be);
    y0 = y0 > 0.f ? y0 : 0.f;
    y1 = y1 > 0.f ? y1 : 0.f;
    // dropout: element index i = row*S + col, JAX partitionable threefry
    uint32_t i0 = (uint32_t)((2 * t) * S + d);
    float r0 = jax_uniform01(k0, k1, i0);
    float r1 = jax_uniform01(k0, k1, i0 + (uint32_t)S);
    y0 = (r0 < 0.9f) ? y0 * (1.0f / 0.9f) : 0.f;
    y1 = (r1 < 0.9f) ? y1 * (1.0f / 0.9f) : 0.f;
    ((float2*)hout)[d * 100 + t] = make_float2(y0, y1);
  }
}

// ---------------- final lin + plain BN, write row-major to d_out ----------------
__global__ __launch_bounds__(128) void final_bn_kernel(
    const float* __restrict__ hin, float* __restrict__ out,
    const int* __restrict__ ptr, const int* __restrict__ ssrc, const float* __restrict__ swv,
    const float* __restrict__ bias, int col_base) {
  const int d = blockIdx.x;
  const int t = threadIdx.x;
  const int g = col_base + d;
  const int e0 = ptr[g], e1 = ptr[g + 1];
  const float2* __restrict__ hin2 = (const float2*)hin;
  float a0 = 0.f, a1 = 0.f;
  if (t < 100) {
    for (int e = e0; e < e1; ++e) {
      int sA = ssrc[e]; float wA = swv[e];
      float2 hA = hin2[sA * 100 + t];
      a0 = fmaf(hA.x, wA, a0); a1 = fmaf(hA.y, wA, a1);
    }
    float bb = bias[g];
    a0 += bb; a1 += bb;
  }
  float s = a0 + a1;
  float q = a0 * a0 + a1 * a1;
#pragma unroll
  for (int o = 32; o > 0; o >>= 1) { s += __shfl_down(s, o, 64); q += __shfl_down(q, o, 64); }
  __shared__ float shs[2], shq[2];
  if ((t & 63) == 0) { shs[t >> 6] = s; shq[t >> 6] = q; }
  __syncthreads();
  float sum = shs[0] + shs[1];
  float ssq = shq[0] + shq[1];
  float m = sum * (1.0f / 200.0f);
  float v = ssq * (1.0f / 200.0f) - m * m;
  if (v < 0.f) v = 0.f;
  float rstd = 1.0f / sqrtf(v + 1e-5f);
  if (t < 100) {
    out[(2 * t) * 469 + d]     = (a0 - m) * rstd;
    out[(2 * t + 1) * 469 + d] = (a1 - m) * rstd;
  }
}

extern "C" void kernel_launch(void* const* d_in, const int* in_sizes, int n_in,
                              void* d_out, int out_size, void* d_ws, size_t ws_size,
                              hipStream_t stream) {
  const float* x     = (const float*)d_in[0];
  const int*   edges = (const int*)d_in[1];
  const float* wmu   = (const float*)d_in[2];
  const float* wls   = (const float*)d_in[3];
  const float* bias  = (const float*)d_in[4];
  const float* gamma = (const float*)d_in[5];
  const float* beta  = (const float*)d_in[6];
  float* out = (float*)d_out;
  const int* srcs = edges;
  const int* dsts = edges + NNZ_ALL;

  char* p = (char*)d_ws;
  auto alloc = [&](size_t bytes) { char* r = p; p += (bytes + 255) & ~(size_t)255; return r; };
  float* A      = (float*)alloc((size_t)6000000 * 4);   // 30000 cols x 200
  float* Bf     = (float*)alloc((size_t)6000000 * 4);   // 30000 cols x 200
  float* C      = (float*)alloc((size_t)3000000 * 4);   // 15000 cols x 200 (pool outputs)
  int*   counts = (int*)alloc((size_t)OUT_ALL * 4);
  int*   ptr    = (int*)alloc((size_t)(OUT_ALL + 1) * 4);
  int*   cursor = (int*)alloc((size_t)OUT_ALL * 4);
  int*   bsums  = (int*)alloc((size_t)512 * 4);
  int*   ssrc   = (int*)alloc((size_t)NNZ_ALL * 4);
  float* swv    = (float*)alloc((size_t)NNZ_ALL * 4);
  float* klp    = (float*)alloc((size_t)512 * 4);

  // stage dropout keys: fold_in(key(1234), 100+st) = threefry2x32((0,1234),(0,100+st))
  uint32_t k0s[6], k1s[6];
  for (int st = 0; st < 6; ++st) {
    uint32_t a = 0u, b = (uint32_t)(100 + st);
    tf2x32(0u, 1234u, a, b);
    k0s[st] = a; k1s[st] = b;
  }

  hipMemsetAsync(counts, 0, (size_t)OUT_ALL * 4, stream);
  transpose_kernel<<<dim3(938, 7), dim3(32, 8), 0, stream>>>(x, A);
  hist_kernel<<<(NNZ_ALL + 255) / 256 + 1, 256, 0, stream>>>(dsts, counts);
  scan1_kernel<<<NB1, 256, 0, stream>>>(counts, ptr, bsums);
  scan2_kernel<<<1, 512, 0, stream>>>(bsums);
  scan3_kernel<<<NB1, 256, 0, stream>>>(ptr, bsums, cursor);
  scatter_kernel<<<(NNZ_ALL + 255) / 256 + 1, 256, 0, stream>>>(srcs, dsts, wmu, cursor, ssrc, swv);
  kl_partial_kernel<<<512, 256, 0, stream>>>(wmu, wls, klp);
  kl_final_kernel<<<1, 512, 0, stream>>>(klp, out + 200 * 469);

  const int S[7]       = {30000, 15000, 7500, 3750, 1875, 938, 469};
  const int OUT_OFF[14] = {0, 30000, 45000, 60000, 67500, 75000, 78750,
                           82500, 84375, 86250, 87188, 88126, 88595, 89064};
  const int BN_OFF[7]  = {0, 30000, 45000, 52500, 56250, 58125, 59063};

  // stage 0: lin layer 0 on x^T: A -> Bf (fused BN/ReLU/drop)
  lin_bn_drop_kernel<<<30000, 128, 0, stream>>>(A, Bf, ptr, ssrc, swv, bias, gamma, beta,
                                                OUT_OFF[0], BN_OFF[0], S[0], k0s[0], k1s[0]);
  float* cur = Bf;
  float* alt = A;
  for (int st = 1; st <= 5; ++st) {
    int li_p = 2 * st - 1, li_l = 2 * st;
    pool_kernel<<<S[st], 128, 0, stream>>>(cur, C, ptr, ssrc, swv, bias, OUT_OFF[li_p]);
    lin_bn_drop_kernel<<<S[st], 128, 0, stream>>>(C, alt, ptr, ssrc, swv, bias, gamma, beta,
                                                  OUT_OFF[li_l], BN_OFF[st], S[st],
                                                  k0s[st], k1s[st]);
    float* tmp = cur; cur = alt; alt = tmp;
  }
  // stage 6: pool layer 11, then final lin 12 + plain BN -> d_out (row-major)
  pool_kernel<<<469, 128, 0, stream>>>(cur, C, ptr, ssrc, swv, bias, OUT_OFF[11]);
  final_bn_kernel<<<469, 128, 0, stream>>>(C, out, ptr, ssrc, swv, bias, OUT_OFF[12]);
}